// Round 8
// baseline (616.818 us; speedup 1.0000x reference)
//
#include <hip/hip_runtime.h>
#include <hip/hip_bf16.h>

__device__ __forceinline__ float lrelu02(float v) { return v > 0.f ? v : 0.2f * v; }

// manual bf16 <-> f32 (RNE); finite data only
__device__ __forceinline__ float bf2f(unsigned short u) {
    union { unsigned int i; float f; } v; v.i = ((unsigned int)u) << 16; return v.f;
}
__device__ __forceinline__ unsigned short f2bf(float f) {
    union { float f; unsigned int i; } v; v.f = f;
    unsigned int x = v.i;
    return (unsigned short)((x + 0x7fffu + ((x >> 16) & 1u)) >> 16);
}
// packed-pair bf16 extract
__device__ __forceinline__ float blo(unsigned int u) {
    union { unsigned int i; float f; } v; v.i = u << 16; return v.f;
}
__device__ __forceinline__ float bhi(unsigned int u) {
    union { unsigned int i; float f; } v; v.i = u & 0xffff0000u; return v.f;
}

typedef float f32x4 __attribute__((ext_vector_type(4)));
typedef short s16x8 __attribute__((ext_vector_type(8)));

// ---------- fused: CSR rank pass + layer-1 dense via MFMA ----------
// (r5: MFMA rewrite verified — absmax held 0.0039, gemm1 off the top-5.)
__global__ __launch_bounds__(512) void gemm1_k(
    const float* __restrict__ x, const float* __restrict__ W1,
    const float* __restrict__ aw_s, const float* __restrict__ aw_d,
    unsigned short* __restrict__ h1b, float* __restrict__ as1, float* __restrict__ ad1, int N,
    const int* __restrict__ ei, int E, int* __restrict__ deg, int* __restrict__ rank)
{
    // --- rank slice (grid-stride over E+N edges); overlaps with W staging + MFMA ---
    {
        const int total = E + N;
        const int stride = gridDim.x * 512;
        for (int e = blockIdx.x * 512 + threadIdx.x; e < total; e += stride) {
            int d = (e < E) ? ei[E + e] : (e - E);
            rank[e] = atomicAdd(&deg[d], 1);
        }
    }

    // --- stage W1 transposed as bf16: Wt[col][k ^ ((col&7)<<3)] ---
    __shared__ unsigned short Wt[128 * 128];   // 32 KB
    {
        const float4* W4 = (const float4*)W1;
        for (int i = threadIdx.x; i < 128 * 32; i += 512) {
            float4 f = W4[i];                      // row k = i>>5, cols 4t..4t+3
            int k = i >> 5, c4 = (i & 31) * 4;
            #pragma unroll
            for (int j = 0; j < 4; ++j) {
                int col = c4 + j;
                float fv = j == 0 ? f.x : j == 1 ? f.y : j == 2 ? f.z : f.w;
                Wt[col * 128 + (k ^ ((col & 7) << 3))] = f2bf(fv);
            }
        }
    }

    const int lane = threadIdx.x & 63;
    const int wv   = threadIdx.x >> 6;          // 0..7
    const int li   = lane & 15;                 // M-row (A) / N-col (B,D) index
    const int kg   = lane >> 4;                 // k-subchunk 0..3
    const int row0 = blockIdx.x * 128 + wv * 16;

    const int rc = (row0 + li < N) ? (row0 + li) : (N - 1);   // clamped A row
    const float4* xr = (const float4*)(x + (size_t)rc * 128);

    f32x4 acc[8];
    #pragma unroll
    for (int ct = 0; ct < 8; ++ct) acc[ct] = {0.f, 0.f, 0.f, 0.f};

    __syncthreads();

    #pragma unroll
    for (int ks = 0; ks < 4; ++ks) {
        // A fragment: x[rc][ks*32 + kg*8 .. +7] as hi/lo bf16 split
        float4 f0 = xr[ks * 8 + kg * 2];
        float4 f1 = xr[ks * 8 + kg * 2 + 1];
        float xf[8] = {f0.x, f0.y, f0.z, f0.w, f1.x, f1.y, f1.z, f1.w};
        s16x8 ahi, alo;
        #pragma unroll
        for (int j = 0; j < 8; ++j) {
            unsigned short h = f2bf(xf[j]);
            ahi[j] = (short)h;
            alo[j] = (short)f2bf(xf[j] - bf2f(h));
        }
        const int kbase = ks * 32 + kg * 8;
        #pragma unroll
        for (int ct = 0; ct < 8; ++ct) {
            const int col = ct * 16 + li;
            const s16x8 b = *reinterpret_cast<const s16x8*>(
                Wt + col * 128 + (kbase ^ ((col & 7) << 3)));
            acc[ct] = __builtin_amdgcn_mfma_f32_16x16x32_bf16(ahi, b, acc[ct], 0, 0, 0);
            acc[ct] = __builtin_amdgcn_mfma_f32_16x16x32_bf16(alo, b, acc[ct], 0, 0, 0);
        }
    }

    // --- epilogue: attn dots + bf16 h1 write ---
    float aws_[8], awd_[8];
    #pragma unroll
    for (int t = 0; t < 8; ++t) { aws_[t] = aw_s[t * 16 + li]; awd_[t] = aw_d[t * 16 + li]; }

    #pragma unroll
    for (int i = 0; i < 4; ++i) {
        const int gr = row0 + (lane >> 4) * 4 + i;
        const bool valid = gr < N;
        float s0 = acc[0][i] * aws_[0] + acc[1][i] * aws_[1];
        float s1 = acc[2][i] * aws_[2] + acc[3][i] * aws_[3];
        float s2 = acc[4][i] * aws_[4] + acc[5][i] * aws_[5];
        float s3 = acc[6][i] * aws_[6] + acc[7][i] * aws_[7];
        float d0 = acc[0][i] * awd_[0] + acc[1][i] * awd_[1];
        float d1 = acc[2][i] * awd_[2] + acc[3][i] * awd_[3];
        float d2 = acc[4][i] * awd_[4] + acc[5][i] * awd_[5];
        float d3 = acc[6][i] * awd_[6] + acc[7][i] * awd_[7];
        #pragma unroll
        for (int m = 1; m < 16; m <<= 1) {
            s0 += __shfl_xor(s0, m, 16); s1 += __shfl_xor(s1, m, 16);
            s2 += __shfl_xor(s2, m, 16); s3 += __shfl_xor(s3, m, 16);
            d0 += __shfl_xor(d0, m, 16); d1 += __shfl_xor(d1, m, 16);
            d2 += __shfl_xor(d2, m, 16); d3 += __shfl_xor(d3, m, 16);
        }
        if (valid) {
            if (li < 4) {
                float sv = li == 0 ? s0 : li == 1 ? s1 : li == 2 ? s2 : s3;
                float dv = li == 0 ? d0 : li == 1 ? d1 : li == 2 ? d2 : d3;
                as1[gr * 4 + li] = sv;
                ad1[gr * 4 + li] = dv;
            }
            #pragma unroll
            for (int ct = 0; ct < 8; ++ct)
                h1b[(size_t)gr * 128 + ct * 16 + li] = f2bf(acc[ct][i]);
        }
    }
}

// ---------- CSR scan ----------
__global__ __launch_bounds__(256) void blocksum_k(
    const int* __restrict__ deg, int N, int* __restrict__ bsum)
{
    __shared__ int sh[256];
    int i = blockIdx.x * 256 + threadIdx.x;
    sh[threadIdx.x] = (i < N) ? deg[i] : 0;
    __syncthreads();
    for (int off = 128; off; off >>= 1) {
        if (threadIdx.x < off) sh[threadIdx.x] += sh[threadIdx.x + off];
        __syncthreads();
    }
    if (threadIdx.x == 0) bsum[blockIdx.x] = sh[0];
}

__global__ __launch_bounds__(1024) void scanbsum_k(int* __restrict__ bsum, int nb)
{
    __shared__ int buf[1024];
    __shared__ int carry;
    if (threadIdx.x == 0) carry = 0;
    __syncthreads();
    for (int base = 0; base < nb; base += 1024) {
        int i = base + threadIdx.x;
        int v = (i < nb) ? bsum[i] : 0;
        buf[threadIdx.x] = v;
        __syncthreads();
        for (int off = 1; off < 1024; off <<= 1) {
            int t = (threadIdx.x >= off) ? buf[threadIdx.x - off] : 0;
            __syncthreads();
            buf[threadIdx.x] += t;
            __syncthreads();
        }
        if (i < nb) bsum[i] = buf[threadIdx.x] - v + carry;   // exclusive
        __syncthreads();
        if (threadIdx.x == 0) carry += buf[1023];
        __syncthreads();
    }
}

__global__ __launch_bounds__(256) void rowptr_k(
    const int* __restrict__ deg, const int* __restrict__ bsum, int N, int E,
    int* __restrict__ rowptr)
{
    __shared__ int buf[256];
    int i = blockIdx.x * 256 + threadIdx.x;
    int v = (i < N) ? deg[i] : 0;
    buf[threadIdx.x] = v;
    __syncthreads();
    for (int off = 1; off < 256; off <<= 1) {
        int t = (threadIdx.x >= off) ? buf[threadIdx.x - off] : 0;
        __syncthreads();
        buf[threadIdx.x] += t;
        __syncthreads();
    }
    if (i < N) rowptr[i] = bsum[blockIdx.x] + buf[threadIdx.x] - v;
    if (i == 0) rowptr[N] = E + N;
}

// Pure scatter, no atomic (rank already known).
__global__ __launch_bounds__(256) void place_k(
    const int* __restrict__ ei, int E, int N,
    const int* __restrict__ rank, const int* __restrict__ rowptr,
    int* __restrict__ csr)
{
    int e = blockIdx.x * 256 + threadIdx.x;
    if (e >= E + N) return;
    int s, d;
    if (e < E) { s = ei[e]; d = ei[E + e]; } else { s = d = e - E; }
    csr[rowptr[d] + rank[e]] = s;
}

// ---------- layer-1 fused: softmax-aggregate + bias + ELU + gemm2 + attn2 dots ----------
// r7 post-mortem: per-lane work assignment is right (VALU 28%) but the dynamic loop had
// ~2-3 loads in flight/wave (csr -> dependent as1/h1b chain, no unroll) -> latency-bound
// at 310us (occupancy 82%, HBM 10%). r5's 112us came from 16 independent h1b loads in
// flight. Fix: 16-edge chunks with explicit 4x unroll — phase 1 issues 4 csr loads,
// phase 2 issues all 8 dependent loads (4 as1 + 4 h1b uint4), phase 3 exps+FMAs.
// MLP/wave ~3 -> ~8-12. Sentinel (-1 -> row wid, w=0) keeps the tail branchless.
__global__ __launch_bounds__(256) void gat1_k(
    const int* __restrict__ csr, const int* __restrict__ rowptr,
    const float* __restrict__ as1, const float* __restrict__ ad1,
    const unsigned short* __restrict__ h1b, const float* __restrict__ b1,
    const float* __restrict__ W2, const float* __restrict__ aw_s2, const float* __restrict__ aw_d2,
    float* __restrict__ g, float* __restrict__ as2, float* __restrict__ ad2, int N)
{
    const int wid  = (blockIdx.x * 256 + threadIdx.x) >> 6;
    const int lane = threadIdx.x & 63;
    if (wid >= N) return;
    const int start = rowptr[wid], end = rowptr[wid + 1];
    const int grp = lane >> 4;      // edge slot 0..3
    const int t   = lane & 15;
    const int hh  = t >> 2;         // head 0..3
    const int c0  = hh * 32 + (t & 3) * 8;   // first of this lane's 8 cols

    const float adh = ad1[(size_t)wid * 4 + hh];
    const float mh  = lrelu02(as1[(size_t)wid * 4 + hh] + adh);  // self-logit offset

    float den = 0.f;
    float acc[8];
    #pragma unroll
    for (int j = 0; j < 8; ++j) acc[j] = 0.f;

    for (int k = start; k < end; k += 16) {
        int   sv0, sv1, sv2, sv3;
        {
            const int i0 = k + grp, i1 = k + 4 + grp, i2 = k + 8 + grp, i3 = k + 12 + grp;
            sv0 = (i0 < end) ? csr[i0] : -1;
            sv1 = (i1 < end) ? csr[i1] : -1;
            sv2 = (i2 < end) ? csr[i2] : -1;
            sv3 = (i3 < end) ? csr[i3] : -1;
        }
        const int sc0 = sv0 < 0 ? wid : sv0;
        const int sc1 = sv1 < 0 ? wid : sv1;
        const int sc2 = sv2 < 0 ? wid : sv2;
        const int sc3 = sv3 < 0 ? wid : sv3;
        // issue ALL dependent loads before consuming any (MLP)
        const float a0 = as1[(size_t)sc0 * 4 + hh];
        const float a1 = as1[(size_t)sc1 * 4 + hh];
        const float a2 = as1[(size_t)sc2 * 4 + hh];
        const float a3 = as1[(size_t)sc3 * 4 + hh];
        const uint4 p0 = *(const uint4*)(h1b + (size_t)sc0 * 128 + c0);
        const uint4 p1 = *(const uint4*)(h1b + (size_t)sc1 * 128 + c0);
        const uint4 p2 = *(const uint4*)(h1b + (size_t)sc2 * 128 + c0);
        const uint4 p3 = *(const uint4*)(h1b + (size_t)sc3 * 128 + c0);

        const float w0 = sv0 >= 0 ? __expf(lrelu02(a0 + adh) - mh) : 0.f;
        const float w1 = sv1 >= 0 ? __expf(lrelu02(a1 + adh) - mh) : 0.f;
        const float w2 = sv2 >= 0 ? __expf(lrelu02(a2 + adh) - mh) : 0.f;
        const float w3 = sv3 >= 0 ? __expf(lrelu02(a3 + adh) - mh) : 0.f;
        den += w0 + w1 + w2 + w3;

        acc[0] = fmaf(w0, blo(p0.x), acc[0]); acc[1] = fmaf(w0, bhi(p0.x), acc[1]);
        acc[2] = fmaf(w0, blo(p0.y), acc[2]); acc[3] = fmaf(w0, bhi(p0.y), acc[3]);
        acc[4] = fmaf(w0, blo(p0.z), acc[4]); acc[5] = fmaf(w0, bhi(p0.z), acc[5]);
        acc[6] = fmaf(w0, blo(p0.w), acc[6]); acc[7] = fmaf(w0, bhi(p0.w), acc[7]);

        acc[0] = fmaf(w1, blo(p1.x), acc[0]); acc[1] = fmaf(w1, bhi(p1.x), acc[1]);
        acc[2] = fmaf(w1, blo(p1.y), acc[2]); acc[3] = fmaf(w1, bhi(p1.y), acc[3]);
        acc[4] = fmaf(w1, blo(p1.z), acc[4]); acc[5] = fmaf(w1, bhi(p1.z), acc[5]);
        acc[6] = fmaf(w1, blo(p1.w), acc[6]); acc[7] = fmaf(w1, bhi(p1.w), acc[7]);

        acc[0] = fmaf(w2, blo(p2.x), acc[0]); acc[1] = fmaf(w2, bhi(p2.x), acc[1]);
        acc[2] = fmaf(w2, blo(p2.y), acc[2]); acc[3] = fmaf(w2, bhi(p2.y), acc[3]);
        acc[4] = fmaf(w2, blo(p2.z), acc[4]); acc[5] = fmaf(w2, bhi(p2.z), acc[5]);
        acc[6] = fmaf(w2, blo(p2.w), acc[6]); acc[7] = fmaf(w2, bhi(p2.w), acc[7]);

        acc[0] = fmaf(w3, blo(p3.x), acc[0]); acc[1] = fmaf(w3, bhi(p3.x), acc[1]);
        acc[2] = fmaf(w3, blo(p3.y), acc[2]); acc[3] = fmaf(w3, bhi(p3.y), acc[3]);
        acc[4] = fmaf(w3, blo(p3.z), acc[4]); acc[5] = fmaf(w3, bhi(p3.z), acc[5]);
        acc[6] = fmaf(w3, blo(p3.w), acc[6]); acc[7] = fmaf(w3, bhi(p3.w), acc[7]);
    }

    // cross-group reduce (groups processed disjoint edge subsets; den duplicates
    // across the 4 octet-lanes of a head are identical, not summed)
    den += __shfl_xor(den, 16); den += __shfl_xor(den, 32);
    #pragma unroll
    for (int j = 0; j < 8; ++j) {
        acc[j] += __shfl_xor(acc[j], 16);
        acc[j] += __shfl_xor(acc[j], 32);
    }

    const float rd = 1.f / (den + 1e-16f);

    // bias + ELU on this lane's 8 cols
    float v[8];
    #pragma unroll
    for (int j = 0; j < 8; ++j) {
        float vv = acc[j] * rd + b1[c0 + j];
        v[j] = vv > 0.f ? vv : expm1f(vv);
    }

    // fused gemm2: p_j = sum over this lane's 8 cols of elu * W2[col][j]
    float p0 = 0.f, p1 = 0.f, p2 = 0.f, p3 = 0.f, p4 = 0.f, p5 = 0.f, p6 = 0.f, p7 = 0.f;
    #pragma unroll
    for (int c = 0; c < 8; ++c) {
        const float4 wa = *(const float4*)(W2 + (size_t)(c0 + c) * 8);
        const float4 wb = *(const float4*)(W2 + (size_t)(c0 + c) * 8 + 4);
        p0 += v[c] * wa.x; p1 += v[c] * wa.y; p2 += v[c] * wa.z; p3 += v[c] * wa.w;
        p4 += v[c] * wb.x; p5 += v[c] * wb.y; p6 += v[c] * wb.z; p7 += v[c] * wb.w;
    }
    // reduce across the 16 lanes of a group (covers all 128 cols); groups identical
    #pragma unroll
    for (int m = 1; m < 16; m <<= 1) {
        p0 += __shfl_xor(p0, m, 16); p1 += __shfl_xor(p1, m, 16);
        p2 += __shfl_xor(p2, m, 16); p3 += __shfl_xor(p3, m, 16);
        p4 += __shfl_xor(p4, m, 16); p5 += __shfl_xor(p5, m, 16);
        p6 += __shfl_xor(p6, m, 16); p7 += __shfl_xor(p7, m, 16);
    }

    if (lane == 0) {
        float4 g0 = {p0, p1, p2, p3};
        float4 g1 = {p4, p5, p6, p7};
        *(float4*)(g + (size_t)wid * 8)     = g0;
        *(float4*)(g + (size_t)wid * 8 + 4) = g1;
        const float4 s0 = *(const float4*)(aw_s2);
        const float4 s1 = *(const float4*)(aw_s2 + 4);
        const float4 d0 = *(const float4*)(aw_d2);
        const float4 d1 = *(const float4*)(aw_d2 + 4);
        as2[wid] = p0 * s0.x + p1 * s0.y + p2 * s0.z + p3 * s0.w
                 + p4 * s1.x + p5 * s1.y + p6 * s1.z + p7 * s1.w;
        ad2[wid] = p0 * d0.x + p1 * d0.y + p2 * d0.z + p3 * d0.w
                 + p4 * d1.x + p5 * d1.y + p6 * d1.z + p7 * d1.w;
    }
}

// ---------- layer-2 single-pass softmax+aggregate+epilogue: one wave per dst ----------
__global__ __launch_bounds__(256) void gat2_k(
    const int* __restrict__ csr, const int* __restrict__ rowptr,
    const float* __restrict__ as2, const float* __restrict__ ad2,
    const float* __restrict__ g, const float* __restrict__ b2_,
    const float* __restrict__ Wlin, const float* __restrict__ blin,
    float* __restrict__ out, int N)
{
    const int wid  = (blockIdx.x * 256 + threadIdx.x) >> 6;
    const int lane = threadIdx.x & 63;
    if (wid >= N) return;
    const int start = rowptr[wid], end = rowptr[wid + 1];
    const int i8  = lane & 7;
    const int grp = lane >> 3;
    const float adh = ad2[wid];
    const float mh  = lrelu02(as2[wid] + adh);
    float den = 0.f, acc = 0.f;
    int k0 = start;
    for (; k0 + 8 <= end; k0 += 8) {
        int s = csr[k0 + i8];
        float w = __expf(lrelu02(as2[s] + adh) - mh);
        den += w;
        int   se = __shfl(s, grp, 8);
        float we = __shfl(w, grp, 8);
        acc = fmaf(we, g[(size_t)se * 8 + i8], acc);
    }
    int cnt = end - k0;
    if (cnt > 0) {
        int s = (i8 < cnt) ? csr[k0 + i8] : wid;
        float w = (i8 < cnt) ? __expf(lrelu02(as2[s] + adh) - mh) : 0.f;
        den += w;
        int   se = __shfl(s, grp, 8);
        float we = __shfl(w, grp, 8);
        acc = fmaf(we, g[(size_t)se * 8 + i8], acc);
    }
    den += __shfl_xor(den, 1); den += __shfl_xor(den, 2); den += __shfl_xor(den, 4);
    acc += __shfl_xor(acc, 8); acc += __shfl_xor(acc, 16); acc += __shfl_xor(acc, 32);
    float v = acc / (den + 1e-16f) + b2_[i8];
    v = v > 0.f ? v : expm1f(v);
    float t = v * Wlin[i8];
    t += __shfl_xor(t, 1); t += __shfl_xor(t, 2); t += __shfl_xor(t, 4);
    if (lane == 0) out[wid] = 1.f / (1.f + __expf(-(t + blin[0])));
}

extern "C" void kernel_launch(void* const* d_in, const int* in_sizes, int n_in,
                              void* d_out, int out_size, void* d_ws, size_t ws_size,
                              hipStream_t stream)
{
    (void)n_in; (void)out_size; (void)ws_size;
    const float* x    = (const float*)d_in[0];
    const int*   ei   = (const int*)d_in[1];
    // d_in[2] = edge_attr, ignored
    const float* W1   = (const float*)d_in[3];
    const float* as1w = (const float*)d_in[4];
    const float* ad1w = (const float*)d_in[5];
    const float* b1   = (const float*)d_in[6];
    const float* W2   = (const float*)d_in[7];
    const float* as2w = (const float*)d_in[8];
    const float* ad2w = (const float*)d_in[9];
    const float* b2v  = (const float*)d_in[10];
    const float* Wlin = (const float*)d_in[11];
    const float* blin = (const float*)d_in[12];

    const int N = in_sizes[0] / 128;
    const int E = in_sizes[1] / 2;
    const int total = E + N;

    // workspace layout
    float* p = (float*)d_ws;
    unsigned short* h1b = (unsigned short*)p; p += (size_t)N * 64;  // N*128 bf16
    float* as1  = p; p += (size_t)N * 4;
    float* ad1  = p; p += (size_t)N * 4;
    float* g    = p; p += (size_t)N * 8;
    float* as2  = p; p += (size_t)N;
    float* ad2  = p; p += (size_t)N;
    int* deg    = (int*)p; p += (size_t)N;
    int* rowptr = (int*)p; p += (size_t)N + 1;
    int* bsum   = (int*)p; p += ((size_t)N + 255) / 256;
    int* rank   = (int*)p; p += (size_t)total;
    int* csr    = (int*)p; p += (size_t)total;

    const int eb = (total + 255) / 256;
    const int nb = (N + 255) / 256;

    hipMemsetAsync(deg, 0, (size_t)N * sizeof(int), stream);
    // fused: rank pass + layer-1 GEMM on the matrix pipe (MFMA bf16 hi/lo split)
    gemm1_k<<<(N + 127) / 128, 512, 0, stream>>>(x, W1, as1w, ad1w, h1b, as1, ad1, N,
                                                 ei, E, deg, rank);
    blocksum_k<<<nb, 256, 0, stream>>>(deg, N, bsum);
    scanbsum_k<<<1, 1024, 0, stream>>>(bsum, nb);
    rowptr_k<<<nb, 256, 0, stream>>>(deg, bsum, N, E, rowptr);
    place_k<<<eb, 256, 0, stream>>>(ei, E, N, rank, rowptr, csr);

    // layer 1: softmax + aggregate + bias + ELU + gemm2 + attn2 dots (fused, 16-edge chunks)
    gat1_k<<<(N * 64 + 255) / 256, 256, 0, stream>>>(csr, rowptr, as1, ad1, h1b, b1,
                                                     W2, as2w, ad2w, g, as2, ad2, N);
    // layer 2 + epilogue
    gat2_k<<<(N * 64 + 255) / 256, 256, 0, stream>>>(csr, rowptr, as2, ad2, g, b2v, Wlin, blin,
                                                     (float*)d_out, N);
}

// Round 9
// 431.101 us; speedup vs baseline: 1.4308x; 1.4308x over previous
//
#include <hip/hip_runtime.h>
#include <hip/hip_bf16.h>

__device__ __forceinline__ float lrelu02(float v) { return v > 0.f ? v : 0.2f * v; }

// manual bf16 <-> f32 (RNE); finite data only
__device__ __forceinline__ float bf2f(unsigned short u) {
    union { unsigned int i; float f; } v; v.i = ((unsigned int)u) << 16; return v.f;
}
__device__ __forceinline__ unsigned short f2bf(float f) {
    union { float f; unsigned int i; } v; v.f = f;
    unsigned int x = v.i;
    return (unsigned short)((x + 0x7fffu + ((x >> 16) & 1u)) >> 16);
}
// packed-pair bf16 extract
__device__ __forceinline__ float blo(unsigned int u) {
    union { unsigned int i; float f; } v; v.i = u << 16; return v.f;
}
__device__ __forceinline__ float bhi(unsigned int u) {
    union { unsigned int i; float f; } v; v.i = u & 0xffff0000u; return v.f;
}

typedef float f32x4 __attribute__((ext_vector_type(4)));
typedef short s16x8 __attribute__((ext_vector_type(8)));

// ---------- fused: CSR rank pass + layer-1 dense via MFMA ----------
// (r5: MFMA rewrite verified — absmax held 0.0039. Budget arithmetic r4 vs r5 puts this
// at ~111us — to be diagnosed once its counters surface in the top-5.)
__global__ __launch_bounds__(512) void gemm1_k(
    const float* __restrict__ x, const float* __restrict__ W1,
    const float* __restrict__ aw_s, const float* __restrict__ aw_d,
    unsigned short* __restrict__ h1b, float* __restrict__ as1, float* __restrict__ ad1, int N,
    const int* __restrict__ ei, int E, int* __restrict__ deg, int* __restrict__ rank)
{
    // --- rank slice (grid-stride over E+N edges); overlaps with W staging + MFMA ---
    {
        const int total = E + N;
        const int stride = gridDim.x * 512;
        for (int e = blockIdx.x * 512 + threadIdx.x; e < total; e += stride) {
            int d = (e < E) ? ei[E + e] : (e - E);
            rank[e] = atomicAdd(&deg[d], 1);
        }
    }

    // --- stage W1 transposed as bf16: Wt[col][k ^ ((col&7)<<3)] ---
    __shared__ unsigned short Wt[128 * 128];   // 32 KB
    {
        const float4* W4 = (const float4*)W1;
        for (int i = threadIdx.x; i < 128 * 32; i += 512) {
            float4 f = W4[i];                      // row k = i>>5, cols 4t..4t+3
            int k = i >> 5, c4 = (i & 31) * 4;
            #pragma unroll
            for (int j = 0; j < 4; ++j) {
                int col = c4 + j;
                float fv = j == 0 ? f.x : j == 1 ? f.y : j == 2 ? f.z : f.w;
                Wt[col * 128 + (k ^ ((col & 7) << 3))] = f2bf(fv);
            }
        }
    }

    const int lane = threadIdx.x & 63;
    const int wv   = threadIdx.x >> 6;          // 0..7
    const int li   = lane & 15;                 // M-row (A) / N-col (B,D) index
    const int kg   = lane >> 4;                 // k-subchunk 0..3
    const int row0 = blockIdx.x * 128 + wv * 16;

    const int rc = (row0 + li < N) ? (row0 + li) : (N - 1);   // clamped A row
    const float4* xr = (const float4*)(x + (size_t)rc * 128);

    f32x4 acc[8];
    #pragma unroll
    for (int ct = 0; ct < 8; ++ct) acc[ct] = {0.f, 0.f, 0.f, 0.f};

    __syncthreads();

    #pragma unroll
    for (int ks = 0; ks < 4; ++ks) {
        // A fragment: x[rc][ks*32 + kg*8 .. +7] as hi/lo bf16 split
        float4 f0 = xr[ks * 8 + kg * 2];
        float4 f1 = xr[ks * 8 + kg * 2 + 1];
        float xf[8] = {f0.x, f0.y, f0.z, f0.w, f1.x, f1.y, f1.z, f1.w};
        s16x8 ahi, alo;
        #pragma unroll
        for (int j = 0; j < 8; ++j) {
            unsigned short h = f2bf(xf[j]);
            ahi[j] = (short)h;
            alo[j] = (short)f2bf(xf[j] - bf2f(h));
        }
        const int kbase = ks * 32 + kg * 8;
        #pragma unroll
        for (int ct = 0; ct < 8; ++ct) {
            const int col = ct * 16 + li;
            const s16x8 b = *reinterpret_cast<const s16x8*>(
                Wt + col * 128 + (kbase ^ ((col & 7) << 3)));
            acc[ct] = __builtin_amdgcn_mfma_f32_16x16x32_bf16(ahi, b, acc[ct], 0, 0, 0);
            acc[ct] = __builtin_amdgcn_mfma_f32_16x16x32_bf16(alo, b, acc[ct], 0, 0, 0);
        }
    }

    // --- epilogue: attn dots + bf16 h1 write ---
    float aws_[8], awd_[8];
    #pragma unroll
    for (int t = 0; t < 8; ++t) { aws_[t] = aw_s[t * 16 + li]; awd_[t] = aw_d[t * 16 + li]; }

    #pragma unroll
    for (int i = 0; i < 4; ++i) {
        const int gr = row0 + (lane >> 4) * 4 + i;
        const bool valid = gr < N;
        float s0 = acc[0][i] * aws_[0] + acc[1][i] * aws_[1];
        float s1 = acc[2][i] * aws_[2] + acc[3][i] * aws_[3];
        float s2 = acc[4][i] * aws_[4] + acc[5][i] * aws_[5];
        float s3 = acc[6][i] * aws_[6] + acc[7][i] * aws_[7];
        float d0 = acc[0][i] * awd_[0] + acc[1][i] * awd_[1];
        float d1 = acc[2][i] * awd_[2] + acc[3][i] * awd_[3];
        float d2 = acc[4][i] * awd_[4] + acc[5][i] * awd_[5];
        float d3 = acc[6][i] * awd_[6] + acc[7][i] * awd_[7];
        #pragma unroll
        for (int m = 1; m < 16; m <<= 1) {
            s0 += __shfl_xor(s0, m, 16); s1 += __shfl_xor(s1, m, 16);
            s2 += __shfl_xor(s2, m, 16); s3 += __shfl_xor(s3, m, 16);
            d0 += __shfl_xor(d0, m, 16); d1 += __shfl_xor(d1, m, 16);
            d2 += __shfl_xor(d2, m, 16); d3 += __shfl_xor(d3, m, 16);
        }
        if (valid) {
            if (li < 4) {
                float sv = li == 0 ? s0 : li == 1 ? s1 : li == 2 ? s2 : s3;
                float dv = li == 0 ? d0 : li == 1 ? d1 : li == 2 ? d2 : d3;
                as1[gr * 4 + li] = sv;
                ad1[gr * 4 + li] = dv;
            }
            #pragma unroll
            for (int ct = 0; ct < 8; ++ct)
                h1b[(size_t)gr * 128 + ct * 16 + li] = f2bf(acc[ct][i]);
        }
    }
}

// ---------- CSR scan ----------
__global__ __launch_bounds__(256) void blocksum_k(
    const int* __restrict__ deg, int N, int* __restrict__ bsum)
{
    __shared__ int sh[256];
    int i = blockIdx.x * 256 + threadIdx.x;
    sh[threadIdx.x] = (i < N) ? deg[i] : 0;
    __syncthreads();
    for (int off = 128; off; off >>= 1) {
        if (threadIdx.x < off) sh[threadIdx.x] += sh[threadIdx.x + off];
        __syncthreads();
    }
    if (threadIdx.x == 0) bsum[blockIdx.x] = sh[0];
}

__global__ __launch_bounds__(1024) void scanbsum_k(int* __restrict__ bsum, int nb)
{
    __shared__ int buf[1024];
    __shared__ int carry;
    if (threadIdx.x == 0) carry = 0;
    __syncthreads();
    for (int base = 0; base < nb; base += 1024) {
        int i = base + threadIdx.x;
        int v = (i < nb) ? bsum[i] : 0;
        buf[threadIdx.x] = v;
        __syncthreads();
        for (int off = 1; off < 1024; off <<= 1) {
            int t = (threadIdx.x >= off) ? buf[threadIdx.x - off] : 0;
            __syncthreads();
            buf[threadIdx.x] += t;
            __syncthreads();
        }
        if (i < nb) bsum[i] = buf[threadIdx.x] - v + carry;   // exclusive
        __syncthreads();
        if (threadIdx.x == 0) carry += buf[1023];
        __syncthreads();
    }
}

__global__ __launch_bounds__(256) void rowptr_k(
    const int* __restrict__ deg, const int* __restrict__ bsum, int N, int E,
    int* __restrict__ rowptr)
{
    __shared__ int buf[256];
    int i = blockIdx.x * 256 + threadIdx.x;
    int v = (i < N) ? deg[i] : 0;
    buf[threadIdx.x] = v;
    __syncthreads();
    for (int off = 1; off < 256; off <<= 1) {
        int t = (threadIdx.x >= off) ? buf[threadIdx.x - off] : 0;
        __syncthreads();
        buf[threadIdx.x] += t;
        __syncthreads();
    }
    if (i < N) rowptr[i] = bsum[blockIdx.x] + buf[threadIdx.x] - v;
    if (i == 0) rowptr[N] = E + N;
}

// Pure scatter, no atomic (rank already known).
__global__ __launch_bounds__(256) void place_k(
    const int* __restrict__ ei, int E, int N,
    const int* __restrict__ rank, const int* __restrict__ rowptr,
    int* __restrict__ csr)
{
    int e = blockIdx.x * 256 + threadIdx.x;
    if (e >= E + N) return;
    int s, d;
    if (e < E) { s = ei[e]; d = ei[E + e]; } else { s = d = e - E; }
    csr[rowptr[d] + rank[e]] = s;
}

// ---------- layer-1 fused: softmax-aggregate + bias + ELU + gemm2 + attn2 dots ----------
// r8 post-mortem: VGPR=32 proves the backend re-serialized the hand-unrolled gather
// (load->use pairs, MLP ~2-3) -> 309us, identical to r7. r5's readlane structure (112us)
// was the right one: its fixed-16 unrolled broadcast loop issues 16 independent row-loads
// from register-resident (s,w). This version = r5 + CROSS-CHUNK PREFETCH: next chunk's
// csr+as1 loads are issued before the current chunk's 16-iteration loop (which covers
// their ~600cy latency); next exp computed after. Tail weights prefetched the same way.
__global__ __launch_bounds__(256) void gat1_k(
    const int* __restrict__ csr, const int* __restrict__ rowptr,
    const float* __restrict__ as1, const float* __restrict__ ad1,
    const unsigned short* __restrict__ h1b, const float* __restrict__ b1,
    const float* __restrict__ W2, const float* __restrict__ aw_s2, const float* __restrict__ aw_d2,
    float* __restrict__ g, float* __restrict__ as2, float* __restrict__ ad2, int N)
{
    __shared__ float red[4][8][12];   // [wave][src-lane][j]
    const int wv   = threadIdx.x >> 6;
    const int wid  = (blockIdx.x * 256 + threadIdx.x) >> 6;
    const int lane = threadIdx.x & 63;
    if (wid >= N) return;
    const int start = rowptr[wid], end = rowptr[wid + 1];
    const int i16 = lane & 15;
    const int hh  = lane >> 4;
    const float adh = ad1[wid * 4 + hh];
    const float mh  = lrelu02(as1[wid * 4 + hh] + adh);   // self-logit offset (den >= 1)
    const unsigned short* hb = h1b + lane * 2;

    float den = 0.f, acc0 = 0.f, acc1 = 0.f;

    int k0 = start;
    int cnt = end - k0; cnt = cnt > 16 ? 16 : cnt;        // first chunk (>=1: self loop)
    int   s = (i16 < cnt) ? csr[k0 + i16] : wid;
    float w = (i16 < cnt) ? __expf(lrelu02(as1[(size_t)s * 4 + hh] + adh) - mh) : 0.f;

    while (true) {
        // prefetch next chunk's loads before consuming the current one
        const int k1 = k0 + 16;
        int cnt_n = end - k1; cnt_n = cnt_n > 16 ? 16 : cnt_n;   // may be <= 0
        int   s_n = wid;
        float a_n = 0.f;
        if (cnt_n > 0) {
            s_n = (i16 < cnt_n) ? csr[k1 + i16] : wid;
            a_n = as1[(size_t)s_n * 4 + hh];
        }

        den += w;
        if (cnt == 16) {
            #pragma unroll
            for (int e = 0; e < 16; ++e) {
                int se = __builtin_amdgcn_readlane(s, e);
                float we = __shfl(w, e, 16);
                unsigned int pv = *(const unsigned int*)(hb + (size_t)se * 128);
                acc0 = fmaf(bf2f((unsigned short)pv), we, acc0);
                acc1 = fmaf(bf2f((unsigned short)(pv >> 16)), we, acc1);
            }
        } else {
            for (int e = 0; e < cnt; ++e) {
                int se = __builtin_amdgcn_readlane(s, e);
                float we = __shfl(w, e, 16);
                unsigned int pv = *(const unsigned int*)(hb + (size_t)se * 128);
                acc0 = fmaf(bf2f((unsigned short)pv), we, acc0);
                acc1 = fmaf(bf2f((unsigned short)(pv >> 16)), we, acc1);
            }
        }
        if (cnt_n <= 0) break;
        s = s_n;
        w = (i16 < cnt_n) ? __expf(lrelu02(a_n + adh) - mh) : 0.f;
        k0 = k1; cnt = cnt_n;
    }

    den += __shfl_xor(den, 1); den += __shfl_xor(den, 2);
    den += __shfl_xor(den, 4); den += __shfl_xor(den, 8);
    const float rden = 1.f / (den + 1e-16f);
    float v0 = acc0 * rden + b1[lane * 2];
    float v1 = acc1 * rden + b1[lane * 2 + 1];
    v0 = v0 > 0.f ? v0 : expm1f(v0);
    v1 = v1 > 0.f ? v1 : expm1f(v1);

    // --- fused gemm2: g_j = sum_k elu_out[k] * W2[k][j] (k = 2*lane, 2*lane+1) ---
    const float4 a0 = *(const float4*)(W2 + 16 * lane);
    const float4 a1 = *(const float4*)(W2 + 16 * lane + 4);
    const float4 b0 = *(const float4*)(W2 + 16 * lane + 8);
    const float4 b1v = *(const float4*)(W2 + 16 * lane + 12);
    float p[8];
    p[0] = v0 * a0.x + v1 * b0.x;  p[1] = v0 * a0.y + v1 * b0.y;
    p[2] = v0 * a0.z + v1 * b0.z;  p[3] = v0 * a0.w + v1 * b0.w;
    p[4] = v0 * a1.x + v1 * b1v.x; p[5] = v0 * a1.y + v1 * b1v.y;
    p[6] = v0 * a1.z + v1 * b1v.z; p[7] = v0 * a1.w + v1 * b1v.w;
    #pragma unroll
    for (int j = 0; j < 8; ++j) {
        p[j] += __shfl_xor(p[j], 8);
        p[j] += __shfl_xor(p[j], 16);
        p[j] += __shfl_xor(p[j], 32);
    }
    if (lane < 8) {
        #pragma unroll
        for (int j = 0; j < 8; ++j) red[wv][lane][j] = p[j];
    }
    if (lane < 8) {
        float gj = 0.f;
        #pragma unroll
        for (int c = 0; c < 8; ++c) gj += red[wv][c][lane];
        g[(size_t)wid * 8 + lane] = gj;
        float ts = gj * aw_s2[lane], td = gj * aw_d2[lane];
        ts += __shfl_xor(ts, 1); ts += __shfl_xor(ts, 2); ts += __shfl_xor(ts, 4);
        td += __shfl_xor(td, 1); td += __shfl_xor(td, 2); td += __shfl_xor(td, 4);
        if (lane == 0) { as2[wid] = ts; ad2[wid] = td; }
    }
}

// ---------- layer-2 single-pass softmax+aggregate+epilogue: one wave per dst ----------
// Same cross-chunk prefetch as gat1: per 8-edge chunk the chain csr->as2->exp->shfl->
// g-load->fma is fully serial; prefetching the next chunk's csr+as2 hides it.
__global__ __launch_bounds__(256) void gat2_k(
    const int* __restrict__ csr, const int* __restrict__ rowptr,
    const float* __restrict__ as2, const float* __restrict__ ad2,
    const float* __restrict__ g, const float* __restrict__ b2_,
    const float* __restrict__ Wlin, const float* __restrict__ blin,
    float* __restrict__ out, int N)
{
    const int wid  = (blockIdx.x * 256 + threadIdx.x) >> 6;
    const int lane = threadIdx.x & 63;
    if (wid >= N) return;
    const int start = rowptr[wid], end = rowptr[wid + 1];
    const int i8  = lane & 7;
    const int grp = lane >> 3;
    const float adh = ad2[wid];
    const float mh  = lrelu02(as2[wid] + adh);
    float den = 0.f, acc = 0.f;

    int k0 = start;
    int cnt = end - k0; cnt = cnt > 8 ? 8 : cnt;
    int   s = (i8 < cnt) ? csr[k0 + i8] : wid;
    float w = (i8 < cnt) ? __expf(lrelu02(as2[s] + adh) - mh) : 0.f;

    while (true) {
        const int k1 = k0 + 8;
        int cnt_n = end - k1; cnt_n = cnt_n > 8 ? 8 : cnt_n;
        int   s_n = wid;
        float a_n = 0.f;
        if (cnt_n > 0) {
            s_n = (i8 < cnt_n) ? csr[k1 + i8] : wid;
            a_n = as2[s_n];
        }

        den += w;
        int   se = __shfl(s, grp, 8);
        float we = __shfl(w, grp, 8);
        acc = fmaf(we, g[(size_t)se * 8 + i8], acc);

        if (cnt_n <= 0) break;
        s = s_n;
        w = (i8 < cnt_n) ? __expf(lrelu02(a_n + adh) - mh) : 0.f;
        k0 = k1; cnt = cnt_n;
    }

    den += __shfl_xor(den, 1); den += __shfl_xor(den, 2); den += __shfl_xor(den, 4);
    acc += __shfl_xor(acc, 8); acc += __shfl_xor(acc, 16); acc += __shfl_xor(acc, 32);
    float v = acc / (den + 1e-16f) + b2_[i8];
    v = v > 0.f ? v : expm1f(v);
    float t = v * Wlin[i8];
    t += __shfl_xor(t, 1); t += __shfl_xor(t, 2); t += __shfl_xor(t, 4);
    if (lane == 0) out[wid] = 1.f / (1.f + __expf(-(t + blin[0])));
}

extern "C" void kernel_launch(void* const* d_in, const int* in_sizes, int n_in,
                              void* d_out, int out_size, void* d_ws, size_t ws_size,
                              hipStream_t stream)
{
    (void)n_in; (void)out_size; (void)ws_size;
    const float* x    = (const float*)d_in[0];
    const int*   ei   = (const int*)d_in[1];
    // d_in[2] = edge_attr, ignored
    const float* W1   = (const float*)d_in[3];
    const float* as1w = (const float*)d_in[4];
    const float* ad1w = (const float*)d_in[5];
    const float* b1   = (const float*)d_in[6];
    const float* W2   = (const float*)d_in[7];
    const float* as2w = (const float*)d_in[8];
    const float* ad2w = (const float*)d_in[9];
    const float* b2v  = (const float*)d_in[10];
    const float* Wlin = (const float*)d_in[11];
    const float* blin = (const float*)d_in[12];

    const int N = in_sizes[0] / 128;
    const int E = in_sizes[1] / 2;
    const int total = E + N;

    // workspace layout
    float* p = (float*)d_ws;
    unsigned short* h1b = (unsigned short*)p; p += (size_t)N * 64;  // N*128 bf16
    float* as1  = p; p += (size_t)N * 4;
    float* ad1  = p; p += (size_t)N * 4;
    float* g    = p; p += (size_t)N * 8;
    float* as2  = p; p += (size_t)N;
    float* ad2  = p; p += (size_t)N;
    int* deg    = (int*)p; p += (size_t)N;
    int* rowptr = (int*)p; p += (size_t)N + 1;
    int* bsum   = (int*)p; p += ((size_t)N + 255) / 256;
    int* rank   = (int*)p; p += (size_t)total;
    int* csr    = (int*)p; p += (size_t)total;

    const int eb = (total + 255) / 256;
    const int nb = (N + 255) / 256;

    hipMemsetAsync(deg, 0, (size_t)N * sizeof(int), stream);
    // fused: rank pass + layer-1 GEMM on the matrix pipe (MFMA bf16 hi/lo split)
    gemm1_k<<<(N + 127) / 128, 512, 0, stream>>>(x, W1, as1w, ad1w, h1b, as1, ad1, N,
                                                 ei, E, deg, rank);
    blocksum_k<<<nb, 256, 0, stream>>>(deg, N, bsum);
    scanbsum_k<<<1, 1024, 0, stream>>>(bsum, nb);
    rowptr_k<<<nb, 256, 0, stream>>>(deg, bsum, N, E, rowptr);
    place_k<<<eb, 256, 0, stream>>>(ei, E, N, rank, rowptr, csr);

    // layer 1: softmax + aggregate + bias + ELU + gemm2 + attn2 dots (r5 structure + prefetch)
    gat1_k<<<(N * 64 + 255) / 256, 256, 0, stream>>>(csr, rowptr, as1, ad1, h1b, b1,
                                                     W2, as2w, ad2w, g, as2, ad2, N);
    // layer 2 + epilogue (+ prefetch)
    gat2_k<<<(N * 64 + 255) / 256, 256, 0, stream>>>(csr, rowptr, as2, ad2, g, b2v, Wlin, blin,
                                                     (float*)d_out, N);
}

// Round 11
// 409.679 us; speedup vs baseline: 1.5056x; 1.0523x over previous
//
#include <hip/hip_runtime.h>
#include <hip/hip_bf16.h>

__device__ __forceinline__ float lrelu02(float v) { return v > 0.f ? v : 0.2f * v; }

// manual bf16 <-> f32 (RNE); finite data only
__device__ __forceinline__ float bf2f(unsigned short u) {
    union { unsigned int i; float f; } v; v.i = ((unsigned int)u) << 16; return v.f;
}
__device__ __forceinline__ unsigned short f2bf(float f) {
    union { float f; unsigned int i; } v; v.f = f;
    unsigned int x = v.i;
    return (unsigned short)((x + 0x7fffu + ((x >> 16) & 1u)) >> 16);
}
// fp16 store helper (RNE)
__device__ __forceinline__ unsigned short f2h(float f) {
    union { _Float16 h; unsigned short u; } v; v.h = (_Float16)f; return v.u;
}

typedef float f32x4 __attribute__((ext_vector_type(4)));
typedef short s16x8 __attribute__((ext_vector_type(8)));

// half2 vector type derived from the builtin itself (r10 compile fix: cvt_pkrtz returns
// __fp16x2, NOT _Float16x2 — take decltype so wrapper types match the builtins exactly)
using half2v = decltype(__builtin_amdgcn_cvt_pkrtz(0.f, 0.f));

__device__ __forceinline__ half2v u2h2(unsigned int u) {
    union { unsigned int u; half2v h; } v; v.u = u; return v.h;
}
__device__ __forceinline__ unsigned int h22u(half2v h) {
    union { unsigned int u; half2v h; } v; v.h = h; return v.u;
}

// ---------- rank pass, split out of gemm1 (r9 diagnostics) ----------
// 1.7M atomicAdd-with-return on 100K counters (~17 collisions each). Separate kernel so
// its dur/counters expose the true atomic cost (theory: ~50-90us, L2-serialization-bound).
__global__ __launch_bounds__(256) void rank_k(
    const int* __restrict__ ei, int E, int N,
    int* __restrict__ deg, int* __restrict__ rank)
{
    int e = blockIdx.x * 256 + threadIdx.x;
    if (e >= E + N) return;
    int d = (e < E) ? ei[E + e] : (e - E);
    rank[e] = atomicAdd(&deg[d], 1);
}

// ---------- layer-1 dense via MFMA (pure; rank pass removed) ----------
// (r5: MFMA verified, absmax held. h1 now stored as FP16 — more mantissa than bf16,
// enables v_dot2_f32_f16 aggregation in gat1.)
__global__ __launch_bounds__(512) void gemm1_k(
    const float* __restrict__ x, const float* __restrict__ W1,
    const float* __restrict__ aw_s, const float* __restrict__ aw_d,
    unsigned short* __restrict__ h1b, float* __restrict__ as1, float* __restrict__ ad1, int N)
{
    // --- stage W1 transposed as bf16: Wt[col][k ^ ((col&7)<<3)] ---
    __shared__ unsigned short Wt[128 * 128];   // 32 KB
    {
        const float4* W4 = (const float4*)W1;
        for (int i = threadIdx.x; i < 128 * 32; i += 512) {
            float4 f = W4[i];                      // row k = i>>5, cols 4t..4t+3
            int k = i >> 5, c4 = (i & 31) * 4;
            #pragma unroll
            for (int j = 0; j < 4; ++j) {
                int col = c4 + j;
                float fv = j == 0 ? f.x : j == 1 ? f.y : j == 2 ? f.z : f.w;
                Wt[col * 128 + (k ^ ((col & 7) << 3))] = f2bf(fv);
            }
        }
    }

    const int lane = threadIdx.x & 63;
    const int wv   = threadIdx.x >> 6;          // 0..7
    const int li   = lane & 15;                 // M-row (A) / N-col (B,D) index
    const int kg   = lane >> 4;                 // k-subchunk 0..3
    const int row0 = blockIdx.x * 128 + wv * 16;

    const int rc = (row0 + li < N) ? (row0 + li) : (N - 1);   // clamped A row
    const float4* xr = (const float4*)(x + (size_t)rc * 128);

    f32x4 acc[8];
    #pragma unroll
    for (int ct = 0; ct < 8; ++ct) acc[ct] = {0.f, 0.f, 0.f, 0.f};

    __syncthreads();

    #pragma unroll
    for (int ks = 0; ks < 4; ++ks) {
        // A fragment: x[rc][ks*32 + kg*8 .. +7] as hi/lo bf16 split
        float4 f0 = xr[ks * 8 + kg * 2];
        float4 f1 = xr[ks * 8 + kg * 2 + 1];
        float xf[8] = {f0.x, f0.y, f0.z, f0.w, f1.x, f1.y, f1.z, f1.w};
        s16x8 ahi, alo;
        #pragma unroll
        for (int j = 0; j < 8; ++j) {
            unsigned short h = f2bf(xf[j]);
            ahi[j] = (short)h;
            alo[j] = (short)f2bf(xf[j] - bf2f(h));
        }
        const int kbase = ks * 32 + kg * 8;
        #pragma unroll
        for (int ct = 0; ct < 8; ++ct) {
            const int col = ct * 16 + li;
            const s16x8 b = *reinterpret_cast<const s16x8*>(
                Wt + col * 128 + (kbase ^ ((col & 7) << 3)));
            acc[ct] = __builtin_amdgcn_mfma_f32_16x16x32_bf16(ahi, b, acc[ct], 0, 0, 0);
            acc[ct] = __builtin_amdgcn_mfma_f32_16x16x32_bf16(alo, b, acc[ct], 0, 0, 0);
        }
    }

    // --- epilogue: attn dots + fp16 h1 write ---
    float aws_[8], awd_[8];
    #pragma unroll
    for (int t = 0; t < 8; ++t) { aws_[t] = aw_s[t * 16 + li]; awd_[t] = aw_d[t * 16 + li]; }

    #pragma unroll
    for (int i = 0; i < 4; ++i) {
        const int gr = row0 + (lane >> 4) * 4 + i;
        const bool valid = gr < N;
        float s0 = acc[0][i] * aws_[0] + acc[1][i] * aws_[1];
        float s1 = acc[2][i] * aws_[2] + acc[3][i] * aws_[3];
        float s2 = acc[4][i] * aws_[4] + acc[5][i] * aws_[5];
        float s3 = acc[6][i] * aws_[6] + acc[7][i] * aws_[7];
        float d0 = acc[0][i] * awd_[0] + acc[1][i] * awd_[1];
        float d1 = acc[2][i] * awd_[2] + acc[3][i] * awd_[3];
        float d2 = acc[4][i] * awd_[4] + acc[5][i] * awd_[5];
        float d3 = acc[6][i] * awd_[6] + acc[7][i] * awd_[7];
        #pragma unroll
        for (int m = 1; m < 16; m <<= 1) {
            s0 += __shfl_xor(s0, m, 16); s1 += __shfl_xor(s1, m, 16);
            s2 += __shfl_xor(s2, m, 16); s3 += __shfl_xor(s3, m, 16);
            d0 += __shfl_xor(d0, m, 16); d1 += __shfl_xor(d1, m, 16);
            d2 += __shfl_xor(d2, m, 16); d3 += __shfl_xor(d3, m, 16);
        }
        if (valid) {
            if (li < 4) {
                float sv = li == 0 ? s0 : li == 1 ? s1 : li == 2 ? s2 : s3;
                float dv = li == 0 ? d0 : li == 1 ? d1 : li == 2 ? d2 : d3;
                as1[gr * 4 + li] = sv;
                ad1[gr * 4 + li] = dv;
            }
            #pragma unroll
            for (int ct = 0; ct < 8; ++ct)
                h1b[(size_t)gr * 128 + ct * 16 + li] = f2h(acc[ct][i]);
        }
    }
}

// ---------- CSR scan ----------
__global__ __launch_bounds__(256) void blocksum_k(
    const int* __restrict__ deg, int N, int* __restrict__ bsum)
{
    __shared__ int sh[256];
    int i = blockIdx.x * 256 + threadIdx.x;
    sh[threadIdx.x] = (i < N) ? deg[i] : 0;
    __syncthreads();
    for (int off = 128; off; off >>= 1) {
        if (threadIdx.x < off) sh[threadIdx.x] += sh[threadIdx.x + off];
        __syncthreads();
    }
    if (threadIdx.x == 0) bsum[blockIdx.x] = sh[0];
}

__global__ __launch_bounds__(1024) void scanbsum_k(int* __restrict__ bsum, int nb)
{
    __shared__ int buf[1024];
    __shared__ int carry;
    if (threadIdx.x == 0) carry = 0;
    __syncthreads();
    for (int base = 0; base < nb; base += 1024) {
        int i = base + threadIdx.x;
        int v = (i < nb) ? bsum[i] : 0;
        buf[threadIdx.x] = v;
        __syncthreads();
        for (int off = 1; off < 1024; off <<= 1) {
            int t = (threadIdx.x >= off) ? buf[threadIdx.x - off] : 0;
            __syncthreads();
            buf[threadIdx.x] += t;
            __syncthreads();
        }
        if (i < nb) bsum[i] = buf[threadIdx.x] - v + carry;   // exclusive
        __syncthreads();
        if (threadIdx.x == 0) carry += buf[1023];
        __syncthreads();
    }
}

__global__ __launch_bounds__(256) void rowptr_k(
    const int* __restrict__ deg, const int* __restrict__ bsum, int N, int E,
    int* __restrict__ rowptr)
{
    __shared__ int buf[256];
    int i = blockIdx.x * 256 + threadIdx.x;
    int v = (i < N) ? deg[i] : 0;
    buf[threadIdx.x] = v;
    __syncthreads();
    for (int off = 1; off < 256; off <<= 1) {
        int t = (threadIdx.x >= off) ? buf[threadIdx.x - off] : 0;
        __syncthreads();
        buf[threadIdx.x] += t;
        __syncthreads();
    }
    if (i < N) rowptr[i] = bsum[blockIdx.x] + buf[threadIdx.x] - v;
    if (i == 0) rowptr[N] = E + N;
}

// Pure scatter, no atomic (rank already known).
__global__ __launch_bounds__(256) void place_k(
    const int* __restrict__ ei, int E, int N,
    const int* __restrict__ rank, const int* __restrict__ rowptr,
    int* __restrict__ csr)
{
    int e = blockIdx.x * 256 + threadIdx.x;
    if (e >= E + N) return;
    int s, d;
    if (e < E) { s = ei[e]; d = ei[E + e]; } else { s = d = e - E; }
    csr[rowptr[d] + rank[e]] = s;
}

// ---------- layer-1 fused: softmax-aggregate + bias + ELU + gemm2 + attn2 dots ----------
// r9 post-mortem: gat1 is VALU-ISSUE-bound (100K waves x ~700 insts x 2cy / 1024 SIMDs
// = 57us issue = measured 114us at 47% busy; prefetch/unroll attempts all flat).
// Fix: cut insts/edge ~10 -> ~6 by processing edge PAIRS with v_dot2_f32_f16:
// h1 stored fp16; per 2 edges: 2 readlane + 1 shfl (cvt_pkrtz-packed w pair) + 2 loads
// + 2 v_perm (interleave rows' col-pairs) + 2 fdot2. Weight layout: lane i16 computes w
// for edge i16 at head hh=lane>>4; even lanes hold packed (w_i, w_i+1) via shfl_xor(1).
__global__ __launch_bounds__(256) void gat1_k(
    const int* __restrict__ csr, const int* __restrict__ rowptr,
    const float* __restrict__ as1, const float* __restrict__ ad1,
    const unsigned short* __restrict__ h1b, const float* __restrict__ b1,
    const float* __restrict__ W2, const float* __restrict__ aw_s2, const float* __restrict__ aw_d2,
    float* __restrict__ g, float* __restrict__ as2, float* __restrict__ ad2, int N)
{
    __shared__ float red[4][8][12];   // [wave][src-lane][j]
    const int wv   = threadIdx.x >> 6;
    const int wid  = (blockIdx.x * 256 + threadIdx.x) >> 6;
    const int lane = threadIdx.x & 63;
    if (wid >= N) return;
    const int start = rowptr[wid], end = rowptr[wid + 1];
    const int i16 = lane & 15;
    const int hh  = lane >> 4;
    const float adh = ad1[wid * 4 + hh];
    const float mh  = lrelu02(as1[wid * 4 + hh] + adh);   // self-logit offset (den >= 1)
    const unsigned short* hb = h1b + lane * 2;            // this lane's 2 cols (fp16)

    float den = 0.f, acc0 = 0.f, acc1 = 0.f;

    int   s = 0;
    unsigned int wpku = 0;

    auto pair_step = [&](int p) {
        const int se0 = __builtin_amdgcn_readlane(s, 2 * p);
        const int se1 = __builtin_amdgcn_readlane(s, 2 * p + 1);
        const unsigned int wp = (unsigned int)__shfl((int)wpku, 2 * p, 16);
        const unsigned int pv0 = *(const unsigned int*)(hb + (size_t)se0 * 128);
        const unsigned int pv1 = *(const unsigned int*)(hb + (size_t)se1 * 128);
        const unsigned int lo = __builtin_amdgcn_perm(pv1, pv0, 0x05040100u); // (h_e0[c], h_e1[c])
        const unsigned int hi = __builtin_amdgcn_perm(pv1, pv0, 0x07060302u); // (h_e0[c+1], h_e1[c+1])
        acc0 = __builtin_amdgcn_fdot2(u2h2(wp), u2h2(lo), acc0, false);
        acc1 = __builtin_amdgcn_fdot2(u2h2(wp), u2h2(hi), acc1, false);
    };

    int k0 = start;
    int cnt = end - k0; cnt = cnt > 16 ? 16 : cnt;        // first chunk (>=1: self loop)
    s = (i16 < cnt) ? csr[k0 + i16] : wid;
    float w = (i16 < cnt) ? __expf(lrelu02(as1[(size_t)s * 4 + hh] + adh) - mh) : 0.f;

    while (true) {
        // prefetch next chunk's loads before consuming the current one
        const int k1 = k0 + 16;
        int cnt_n = end - k1; cnt_n = cnt_n > 16 ? 16 : cnt_n;   // may be <= 0
        int   s_n = wid;
        float a_n = 0.f;
        if (cnt_n > 0) {
            s_n = (i16 < cnt_n) ? csr[k1 + i16] : wid;
            a_n = as1[(size_t)s_n * 4 + hh];
        }

        den += w;
        // pack (w_i, w_i+1) on even lanes; pairs stay within the 16-lane head group
        const float wn = __shfl_xor(w, 1);
        wpku = h22u(__builtin_amdgcn_cvt_pkrtz(w, wn));

        if (cnt == 16) {
            #pragma unroll
            for (int p = 0; p < 8; ++p) pair_step(p);
        } else {
            const int pairs = (cnt + 1) >> 1;
            for (int p = 0; p < pairs; ++p) pair_step(p);
        }
        if (cnt_n <= 0) break;
        s = s_n;
        w = (i16 < cnt_n) ? __expf(lrelu02(a_n + adh) - mh) : 0.f;
        k0 = k1; cnt = cnt_n;
    }

    den += __shfl_xor(den, 1); den += __shfl_xor(den, 2);
    den += __shfl_xor(den, 4); den += __shfl_xor(den, 8);
    const float rden = 1.f / (den + 1e-16f);
    float v0 = acc0 * rden + b1[lane * 2];
    float v1 = acc1 * rden + b1[lane * 2 + 1];
    v0 = v0 > 0.f ? v0 : expm1f(v0);
    v1 = v1 > 0.f ? v1 : expm1f(v1);

    // --- fused gemm2: g_j = sum_k elu_out[k] * W2[k][j] (k = 2*lane, 2*lane+1) ---
    const float4 a0 = *(const float4*)(W2 + 16 * lane);
    const float4 a1 = *(const float4*)(W2 + 16 * lane + 4);
    const float4 b0 = *(const float4*)(W2 + 16 * lane + 8);
    const float4 b1v = *(const float4*)(W2 + 16 * lane + 12);
    float p[8];
    p[0] = v0 * a0.x + v1 * b0.x;  p[1] = v0 * a0.y + v1 * b0.y;
    p[2] = v0 * a0.z + v1 * b0.z;  p[3] = v0 * a0.w + v1 * b0.w;
    p[4] = v0 * a1.x + v1 * b1v.x; p[5] = v0 * a1.y + v1 * b1v.y;
    p[6] = v0 * a1.z + v1 * b1v.z; p[7] = v0 * a1.w + v1 * b1v.w;
    #pragma unroll
    for (int j = 0; j < 8; ++j) {
        p[j] += __shfl_xor(p[j], 8);
        p[j] += __shfl_xor(p[j], 16);
        p[j] += __shfl_xor(p[j], 32);
    }
    if (lane < 8) {
        #pragma unroll
        for (int j = 0; j < 8; ++j) red[wv][lane][j] = p[j];
    }
    if (lane < 8) {
        float gj = 0.f;
        #pragma unroll
        for (int c = 0; c < 8; ++c) gj += red[wv][c][lane];
        g[(size_t)wid * 8 + lane] = gj;
        float ts = gj * aw_s2[lane], td = gj * aw_d2[lane];
        ts += __shfl_xor(ts, 1); ts += __shfl_xor(ts, 2); ts += __shfl_xor(ts, 4);
        td += __shfl_xor(td, 1); td += __shfl_xor(td, 2); td += __shfl_xor(td, 4);
        if (lane == 0) { as2[wid] = ts; ad2[wid] = td; }
    }
}

// ---------- layer-2 single-pass softmax+aggregate+epilogue: one wave per dst ----------
__global__ __launch_bounds__(256) void gat2_k(
    const int* __restrict__ csr, const int* __restrict__ rowptr,
    const float* __restrict__ as2, const float* __restrict__ ad2,
    const float* __restrict__ g, const float* __restrict__ b2_,
    const float* __restrict__ Wlin, const float* __restrict__ blin,
    float* __restrict__ out, int N)
{
    const int wid  = (blockIdx.x * 256 + threadIdx.x) >> 6;
    const int lane = threadIdx.x & 63;
    if (wid >= N) return;
    const int start = rowptr[wid], end = rowptr[wid + 1];
    const int i8  = lane & 7;
    const int grp = lane >> 3;
    const float adh = ad2[wid];
    const float mh  = lrelu02(as2[wid] + adh);
    float den = 0.f, acc = 0.f;

    int k0 = start;
    int cnt = end - k0; cnt = cnt > 8 ? 8 : cnt;
    int   s = (i8 < cnt) ? csr[k0 + i8] : wid;
    float w = (i8 < cnt) ? __expf(lrelu02(as2[s] + adh) - mh) : 0.f;

    while (true) {
        const int k1 = k0 + 8;
        int cnt_n = end - k1; cnt_n = cnt_n > 8 ? 8 : cnt_n;
        int   s_n = wid;
        float a_n = 0.f;
        if (cnt_n > 0) {
            s_n = (i8 < cnt_n) ? csr[k1 + i8] : wid;
            a_n = as2[s_n];
        }

        den += w;
        int   se = __shfl(s, grp, 8);
        float we = __shfl(w, grp, 8);
        acc = fmaf(we, g[(size_t)se * 8 + i8], acc);

        if (cnt_n <= 0) break;
        s = s_n;
        w = (i8 < cnt_n) ? __expf(lrelu02(a_n + adh) - mh) : 0.f;
        k0 = k1; cnt = cnt_n;
    }

    den += __shfl_xor(den, 1); den += __shfl_xor(den, 2); den += __shfl_xor(den, 4);
    acc += __shfl_xor(acc, 8); acc += __shfl_xor(acc, 16); acc += __shfl_xor(acc, 32);
    float v = acc / (den + 1e-16f) + b2_[i8];
    v = v > 0.f ? v : expm1f(v);
    float t = v * Wlin[i8];
    t += __shfl_xor(t, 1); t += __shfl_xor(t, 2); t += __shfl_xor(t, 4);
    if (lane == 0) out[wid] = 1.f / (1.f + __expf(-(t + blin[0])));
}

extern "C" void kernel_launch(void* const* d_in, const int* in_sizes, int n_in,
                              void* d_out, int out_size, void* d_ws, size_t ws_size,
                              hipStream_t stream)
{
    (void)n_in; (void)out_size; (void)ws_size;
    const float* x    = (const float*)d_in[0];
    const int*   ei   = (const int*)d_in[1];
    // d_in[2] = edge_attr, ignored
    const float* W1   = (const float*)d_in[3];
    const float* as1w = (const float*)d_in[4];
    const float* ad1w = (const float*)d_in[5];
    const float* b1   = (const float*)d_in[6];
    const float* W2   = (const float*)d_in[7];
    const float* as2w = (const float*)d_in[8];
    const float* ad2w = (const float*)d_in[9];
    const float* b2v  = (const float*)d_in[10];
    const float* Wlin = (const float*)d_in[11];
    const float* blin = (const float*)d_in[12];

    const int N = in_sizes[0] / 128;
    const int E = in_sizes[1] / 2;
    const int total = E + N;

    // workspace layout
    float* p = (float*)d_ws;
    unsigned short* h1b = (unsigned short*)p; p += (size_t)N * 64;  // N*128 fp16
    float* as1  = p; p += (size_t)N * 4;
    float* ad1  = p; p += (size_t)N * 4;
    float* g    = p; p += (size_t)N * 8;
    float* as2  = p; p += (size_t)N;
    float* ad2  = p; p += (size_t)N;
    int* deg    = (int*)p; p += (size_t)N;
    int* rowptr = (int*)p; p += (size_t)N + 1;
    int* bsum   = (int*)p; p += ((size_t)N + 255) / 256;
    int* rank   = (int*)p; p += (size_t)total;
    int* csr    = (int*)p; p += (size_t)total;

    const int eb = (total + 255) / 256;
    const int nb = (N + 255) / 256;

    hipMemsetAsync(deg, 0, (size_t)N * sizeof(int), stream);
    // rank pass split out (diagnostic: expose atomic cost + gemm1 MFMA counters)
    rank_k<<<eb, 256, 0, stream>>>(ei, E, N, deg, rank);
    // layer-1 GEMM on the matrix pipe (MFMA bf16 hi/lo split; fp16 h1 output)
    gemm1_k<<<(N + 127) / 128, 512, 0, stream>>>(x, W1, as1w, ad1w, h1b, as1, ad1, N);
    blocksum_k<<<nb, 256, 0, stream>>>(deg, N, bsum);
    scanbsum_k<<<1, 1024, 0, stream>>>(bsum, nb);
    rowptr_k<<<nb, 256, 0, stream>>>(deg, bsum, N, E, rowptr);
    place_k<<<eb, 256, 0, stream>>>(ei, E, N, rank, rowptr, csr);

    // layer 1: softmax + aggregate + bias + ELU + gemm2 + attn2 dots (fdot2 pairs)
    gat1_k<<<(N * 64 + 255) / 256, 256, 0, stream>>>(csr, rowptr, as1, ad1, h1b, b1,
                                                     W2, as2w, ad2w, g, as2, ad2, N);
    // layer 2 + epilogue
    gat2_k<<<(N * 64 + 255) / 256, 256, 0, stream>>>(csr, rowptr, as2, ad2, g, b2v, Wlin, blin,
                                                     (float*)d_out, N);
}